// Round 14
// baseline (484.047 us; speedup 1.0000x reference)
//
#include <hip/hip_runtime.h>
#include <hip/hip_cooperative_groups.h>
#include <stdint.h>

namespace cg = cooperative_groups;

#define NROW 4096
#define NDIM 128
#define KNEG 4092
#define INF_VAL 1e30f
#define BUCKETS 2048
#define GTOT ((size_t)NROW * (size_t)KNEG)   // 16,760,832 = 1024 * 16368
#define DISTBLKS 1024                         // 32x32 tiles of 128x128
#define DSTR 68

typedef __attribute__((ext_vector_type(8))) short short8;
typedef __attribute__((ext_vector_type(4))) float f32x4;

// ---------------- Threefry-2x32-20, key = (0, 42) ----------------
__device__ __forceinline__ uint32_t rotl32(uint32_t v, int d) {
  return (v << d) | (v >> (32 - d));
}

__device__ __forceinline__ void threefry2x32(uint32_t x0, uint32_t x1,
                                             uint32_t& y0, uint32_t& y1) {
  const uint32_t k0 = 0u, k1 = 42u;
  const uint32_t k2 = 0x1BD11BDAu ^ k0 ^ k1;
  uint32_t v0 = x0 + k0, v1 = x1 + k1;
#define TF_R(r) v0 += v1; v1 = rotl32(v1, r); v1 ^= v0;
  TF_R(13) TF_R(15) TF_R(26) TF_R(6)
  v0 += k1; v1 += k2 + 1u;
  TF_R(17) TF_R(29) TF_R(16) TF_R(24)
  v0 += k2; v1 += k0 + 2u;
  TF_R(13) TF_R(15) TF_R(26) TF_R(6)
  v0 += k0; v1 += k1 + 3u;
  TF_R(17) TF_R(29) TF_R(16) TF_R(24)
  v0 += k1; v1 += k2 + 4u;
  TF_R(13) TF_R(15) TF_R(26) TF_R(6)
  v0 += k2; v1 += k0 + 5u;
#undef TF_R
  y0 = v0; y1 = v1;
}

// partitionable threefry, bits = y1 — verified R1; __logf verified R3
__device__ __forceinline__ float gumbel_ref(uint32_t f) {
  uint32_t y0, y1;
  threefry2x32(0u, f, y0, y1);
  uint32_t m = y1 >> 9;
  float u;
  if (m == 0u) u = 1.17549435e-38f;
  else u = __uint_as_float(m | 0x3f800000u) - 1.0f;
  return -__logf(-__logf(u));
}

__device__ __forceinline__ float softplus_ref(float x) {
  return fmaxf(x, 0.0f) + log1pf(expf(-fabsf(x)));
}

__device__ __forceinline__ ushort f2h(float f) {
  _Float16 h = (_Float16)f;
  return *(ushort*)&h;
}
__device__ __forceinline__ float h2f(ushort u) {
  _Float16 h = *(_Float16*)&u;
  return (float)h;
}
__device__ __forceinline__ float bf2f(ushort u) {
  return __uint_as_float(((uint32_t)u) << 16);
}
__device__ __forceinline__ ushort f2bf(float f) {
  uint32_t u = __float_as_uint(f);
  u += 0x7fffu + ((u >> 16) & 1u);
  return (ushort)(u >> 16);
}

// bucket = bf16 code (monotone & injective for positive floats); every bucket
// holds only exactly-equal values => scatter position IS the exact rank.
__device__ __forceinline__ int bucket_code(ushort code) {
  return min(max((int)code - 0x4000, 0), BUCKETS - 1);
}

// ============================================================================
// Fallback path kernels (R12 verbatim — known-good 192 us pipeline)
// ============================================================================

__global__ __launch_bounds__(64) void prep_kernel(const float* __restrict__ X,
                                                  float* __restrict__ sq,
                                                  ushort* __restrict__ Xbf) {
  int i = blockIdx.x;
  int lane = threadIdx.x;
  float2 v = ((const float2*)(X + (size_t)i * NDIM))[lane];
  float s = v.x * v.x + v.y * v.y;
  for (int o = 32; o > 0; o >>= 1) s += __shfl_down(s, o);
  if (lane == 0) sq[i] = s;
  ushort2 h;
  h.x = f2bf(v.x);
  h.y = f2bf(v.y);
  ((ushort2*)(Xbf + (size_t)i * NDIM))[lane] = h;
}

__global__ __launch_bounds__(256) void dist_gumbel(const ushort* __restrict__ Xbf,
                                                   const float* __restrict__ sq,
                                                   ushort* __restrict__ distb,
                                                   ushort* __restrict__ gh) {
  __shared__ ushort Als[128 * DSTR];
  __shared__ ushort Bls[128 * DSTR];
  const int tid = threadIdx.x;
  const int bi = blockIdx.x >> 5, bj = blockIdx.x & 31;
  const int wave = tid >> 6, lane = tid & 63;
  const int q = lane >> 4, ln = lane & 15;
  const ushort* Ag = Xbf + (size_t)bi * 128 * NDIM;
  const ushort* Bg = Xbf + (size_t)bj * 128 * NDIM;

  f32x4 acc[8][2];
#pragma unroll
  for (int mt = 0; mt < 8; ++mt)
#pragma unroll
    for (int nt = 0; nt < 2; ++nt) acc[mt][nt] = (f32x4){0.f, 0.f, 0.f, 0.f};

  for (int kh = 0; kh < 2; ++kh) {
    if (kh) __syncthreads();
#pragma unroll
    for (int t = 0; t < 4; ++t) {
      int c = tid + 256 * t;
      int r = c >> 3, k8 = (c & 7) << 3;
      *(short8*)&Als[r * DSTR + k8] =
          *(const short8*)(Ag + (size_t)r * NDIM + kh * 64 + k8);
      *(short8*)&Bls[r * DSTR + k8] =
          *(const short8*)(Bg + (size_t)r * NDIM + kh * 64 + k8);
    }
    __syncthreads();
#pragma unroll
    for (int k0 = 0; k0 < 64; k0 += 32) {
      int kf = k0 + q * 8;
      short8 a[8], b[2];
#pragma unroll
      for (int mt = 0; mt < 8; ++mt)
        a[mt] = *(const short8*)&Als[(mt * 16 + ln) * DSTR + kf];
#pragma unroll
      for (int nt = 0; nt < 2; ++nt)
        b[nt] = *(const short8*)&Bls[(wave * 32 + 2 * ln + nt) * DSTR + kf];
#pragma unroll
      for (int mt = 0; mt < 8; ++mt)
#pragma unroll
        for (int nt = 0; nt < 2; ++nt)
          acc[mt][nt] = __builtin_amdgcn_mfma_f32_16x16x32_bf16(
              a[mt], b[nt], acc[mt][nt], 0, 0, 0);
    }
  }

  const int jcol = bj * 128 + wave * 32 + 2 * ln;
  float sqj0 = sq[jcol], sqj1 = sq[jcol + 1];
#pragma unroll
  for (int mt = 0; mt < 8; ++mt) {
    int ibase = bi * 128 + mt * 16 + q * 4;
#pragma unroll
    for (int r = 0; r < 4; ++r) {
      int i = ibase + r;
      float sqi = sq[i];
      float dx = sqrtf(fmaxf(sqi + sqj0 - 2.0f * acc[mt][0][r], 1e-12f));
      float dy = sqrtf(fmaxf(sqi + sqj1 - 2.0f * acc[mt][1][r], 1e-12f));
      uint32_t pack = ((uint32_t)f2bf(dy) << 16) | (uint32_t)f2bf(dx);
      *(uint32_t*)(distb + (size_t)i * NROW + jcol) = pack;
    }
  }

  if (gh) {
    uint32_t b0 = (uint32_t)blockIdx.x * 16368u;
#pragma unroll
    for (int t = 0; t < 16; ++t) {
      int c = tid + 256 * t;
      if (c < 4092) {
        uint32_t f0 = b0 + (uint32_t)c * 4u;
        ushort4 h;
        h.x = f2h(gumbel_ref(f0 + 0u));
        h.y = f2h(gumbel_ref(f0 + 1u));
        h.z = f2h(gumbel_ref(f0 + 2u));
        h.w = f2h(gumbel_ref(f0 + 3u));
        *(ushort4*)(gh + f0) = h;
      }
    }
  }
}

__global__ __launch_bounds__(256) void row_kernel(const ushort* __restrict__ distb,
                                                  const ushort* __restrict__ Gh,
                                                  float4* __restrict__ part) {
  __shared__ alignas(16) float sorted[NROW];
  __shared__ alignas(16) int base[BUCKETS];
  __shared__ float wredf[8];
  __shared__ int wtot[4];
  __shared__ float s_pos[3];
  __shared__ float s_sel[3];

  float* cscore = (float*)base;
  float* cx     = (float*)base + 768;
  int*   crank  = (int*)sorted;
  float* redf   = sorted + 1024;
  int*   redi   = (int*)(sorted + 1280);
  int*   redi2  = (int*)(sorted + 1536);

  const int i = blockIdx.x;
  const int tid = threadIdx.x;
  const int lane = tid & 63, wid = tid >> 6;
  const ushort* row = distb + (size_t)i * NROW;
  const int gbase = i & ~3;

  {
    int4* b4 = (int4*)base;
    b4[tid] = (int4){0, 0, 0, 0};
    b4[tid + 256] = (int4){0, 0, 0, 0};
  }

  ushort cd[16];
  float x[16];
  {
    short8 r0 = *(const short8*)(row + tid * 16);
    short8 r1 = *(const short8*)(row + tid * 16 + 8);
#pragma unroll
    for (int k = 0; k < 8; ++k) {
      cd[k] = (ushort)r0[k];     x[k] = bf2f(cd[k]);
      cd[8 + k] = (ushort)r1[k]; x[8 + k] = bf2f(cd[8 + k]);
    }
  }

  if (tid == (gbase >> 4)) {
    float p[3]; int np = 0;
#pragma unroll
    for (int qq = 0; qq < 4; ++qq) {
      int j = gbase + qq;
      if (j != i) p[np++] = x[j & 15];
    }
    float a = p[0], b = p[1], c = p[2], t_;
    if (a > b) { t_ = a; a = b; b = t_; }
    if (b > c) { t_ = b; b = c; c = t_; }
    if (a > b) { t_ = a; a = b; b = t_; }
    s_pos[0] = a; s_pos[1] = b; s_pos[2] = c;
  }

#pragma unroll
  for (int qq = 0; qq < 16; ++qq) {
    int j = tid * 16 + qq;
    if ((j >> 2) == (i >> 2)) { x[qq] = INF_VAL; cd[qq] = 0x7F80u; }
  }
  __syncthreads();

  int bkt[16];
  int ord[16];
  float ls = 0.f;
#pragma unroll
  for (int qq = 0; qq < 16; ++qq) {
    bkt[qq] = bucket_code(cd[qq]);
    ord[qq] = atomicAdd(&base[bkt[qq]], 1);
    if (x[qq] < 1e29f) ls += x[qq];
  }
  for (int o = 32; o > 0; o >>= 1) ls += __shfl_down(ls, o);
  if (lane == 0) wredf[wid] = ls;
  __syncthreads();
  const float negsum = wredf[0] + wredf[1] + wredf[2] + wredf[3];
  const float mean = negsum / (float)KNEG;

  int c8[8]; int lsum = 0;
#pragma unroll
  for (int qq = 0; qq < 8; ++qq) {
    int t_ = base[tid * 8 + qq];
    c8[qq] = lsum; lsum += t_;
  }
  float ls2 = 0.f;
#pragma unroll
  for (int qq = 0; qq < 16; ++qq)
    if (x[qq] < 1e29f) { float z = x[qq] - mean; ls2 += z * z; }
  int incl = lsum;
  for (int off = 1; off < 64; off <<= 1) {
    int o = __shfl_up(incl, off);
    if (lane >= off) incl += o;
  }
  for (int o = 32; o > 0; o >>= 1) ls2 += __shfl_down(ls2, o);
  if (lane == 63) wtot[wid] = incl;
  if (lane == 0) wredf[4 + wid] = ls2;
  __syncthreads();
  const float var = (wredf[4] + wredf[5] + wredf[6] + wredf[7]) / (float)KNEG;
  const float stdv = sqrtf(var);
  const float rdenom = __frcp_rn(2.0f * stdv * stdv);
  int excl = incl - lsum;
#pragma unroll
  for (int w = 0; w < 4; ++w) if (w < wid) excl += wtot[w];
#pragma unroll
  for (int qq = 0; qq < 8; ++qq) base[tid * 8 + qq] = excl + c8[qq];
  __syncthreads();

#pragma unroll
  for (int qq = 0; qq < 16; ++qq) {
    int p = base[bkt[qq]] + ord[qq];
    sorted[p] = x[qq];
  }
  __syncthreads();

  const uint32_t fbase = (uint32_t)i * (uint32_t)KNEG;
  const ushort* grow = Gh ? (Gh + fbase) : nullptr;
  float t0s = -1e38f, t1s = -1e38f, t2s = -1e38f;
  int   t0r = 0x7fffffff, t1r = 0x7fffffff, t2r = 0x7fffffff;
  float t0x = 0.f, t1x = 0.f, t2x = 0.f;
#pragma unroll
  for (int qq = 0; qq < 16; ++qq) {
    int p = tid + 256 * qq;
    float xv = sorted[p];
    if (p < KNEG) {
      float z = xv - mean;
      float gv = grow ? h2f(grow[p]) : gumbel_ref(fbase + (uint32_t)p);
      float sv = fmaf(z * z, rdenom, gv);
      if (sv > t2s || (sv == t2s && p < t2r)) {
        t2s = sv; t2r = p; t2x = xv;
        if (t2s > t1s || (t2s == t1s && t2r < t1r)) {
          float ts = t1s; int tr = t1r; float tx = t1x;
          t1s = t2s; t1r = t2r; t1x = t2x; t2s = ts; t2r = tr; t2x = tx;
        }
        if (t1s > t0s || (t1s == t0s && t1r < t0r)) {
          float ts = t0s; int tr = t0r; float tx = t0x;
          t0s = t1s; t0r = t1r; t0x = t1x; t1s = ts; t1r = tr; t1x = tx;
        }
      }
    }
  }
  __syncthreads();

  cscore[tid * 3 + 0] = t0s; crank[tid * 3 + 0] = t0r; cx[tid * 3 + 0] = t0x;
  cscore[tid * 3 + 1] = t1s; crank[tid * 3 + 1] = t1r; cx[tid * 3 + 1] = t1x;
  cscore[tid * 3 + 2] = t2s; crank[tid * 3 + 2] = t2r; cx[tid * 3 + 2] = t2x;
  __syncthreads();

  for (int t = 0; t < 3; ++t) {
    float bs = -1e38f; int br = 0x7fffffff; int bidx = 0;
    for (int k = tid; k < 768; k += 256) {
      float s_ = cscore[k]; int r_ = crank[k];
      if (s_ > bs || (s_ == bs && r_ < br)) { bs = s_; br = r_; bidx = k; }
    }
    redf[tid] = bs; redi[tid] = br; redi2[tid] = bidx;
    __syncthreads();
    if (tid < 64) {
      float s0_ = redf[tid]; int r0_ = redi[tid]; int i0_ = redi2[tid];
#pragma unroll
      for (int o = 64; o < 256; o += 64) {
        float s1 = redf[tid + o]; int r1 = redi[tid + o];
        if (s1 > s0_ || (s1 == s0_ && r1 < r0_)) {
          s0_ = s1; r0_ = r1; i0_ = redi2[tid + o];
        }
      }
      for (int off = 32; off > 0; off >>= 1) {
        float s1 = __shfl_down(s0_, off);
        int r1 = __shfl_down(r0_, off);
        int i1 = __shfl_down(i0_, off);
        if (s1 > s0_ || (s1 == s0_ && r1 < r0_)) { s0_ = s1; r0_ = r1; i0_ = i1; }
      }
      if (tid == 0) { s_sel[t] = cx[i0_]; cscore[i0_] = -1e38f; }
    }
    __syncthreads();
  }

  if (tid == 0) {
    float p0 = s_pos[0], p1 = s_pos[1], p2 = s_pos[2];
    float thr = p2 + 0.05f;
    float samp[3]; bool kept[3]; int cnt = 0;
#pragma unroll
    for (int t = 0; t < 3; ++t) {
      samp[t] = s_sel[t];
      kept[t] = samp[t] < thr;
      cnt += kept[t] ? 1 : 0;
    }
    bool any = cnt > 0;
    float pos_loss = 0.5f *
        (softplus_ref(-2.0f * (1.0f - p0)) + softplus_ref(-2.0f * (1.0f - p1)) +
         softplus_ref(-2.0f * (1.0f - p2))) / 3.0f;
    float nsum = 0.0f;
#pragma unroll
    for (int t = 0; t < 3; ++t)
      if (kept[t]) nsum += softplus_ref(20.0f * (1.0f - samp[t]));
    float neg_loss = 0.05f * nsum / (float)(cnt > 0 ? cnt : 1);
    float row_loss = any ? (pos_loss + neg_loss) : 0.0f;
    int first = kept[0] ? 0 : (kept[1] ? 1 : (kept[2] ? 2 : 0));
    float neg0 = samp[first];
    float errv = (any && (p0 < neg0 - 0.1f)) ? 1.0f : 0.0f;
    float4 pr;
    pr.x = row_loss; pr.y = errv; pr.z = p0 + p1 + p2; pr.w = negsum;
    part[i] = pr;
  }
}

__global__ __launch_bounds__(256) void reduce_kernel(const float4* __restrict__ part,
                                                     float* __restrict__ out) {
  __shared__ double wsum[4][4];
  const int tid = threadIdx.x;
  const int lane = tid & 63, wid = tid >> 6;
  double s0 = 0.0, s1 = 0.0, s2 = 0.0, s3 = 0.0;
  for (int k = tid; k < NROW; k += 256) {
    float4 v = part[k];
    s0 += (double)v.x; s1 += (double)v.y; s2 += (double)v.z; s3 += (double)v.w;
  }
  for (int o = 32; o > 0; o >>= 1) {
    s0 += __shfl_down(s0, o); s1 += __shfl_down(s1, o);
    s2 += __shfl_down(s2, o); s3 += __shfl_down(s3, o);
  }
  if (lane == 0) {
    wsum[wid][0] = s0; wsum[wid][1] = s1; wsum[wid][2] = s2; wsum[wid][3] = s3;
  }
  __syncthreads();
  if (tid == 0) {
    double a0 = wsum[0][0] + wsum[1][0] + wsum[2][0] + wsum[3][0];
    double a1 = wsum[0][1] + wsum[1][1] + wsum[2][1] + wsum[3][1];
    double a2 = wsum[0][2] + wsum[1][2] + wsum[2][2] + wsum[3][2];
    double a3 = wsum[0][3] + wsum[1][3] + wsum[2][3] + wsum[3][3];
    out[0] = (float)(a0 / (double)NROW);
    out[1] = (float)(1.0 - a1 / (double)NROW);
    out[2] = (float)(a2 / ((double)NROW * 3.0));
    out[3] = (float)(a3 / ((double)NROW * (double)KNEG));
  }
}

// ============================================================================
// Cooperative single-launch mega kernel: prep -> dist+gumbel -> rows -> reduce
// grid.sync() between phases replaces 3 launch gaps (~40 us at R12). No
// per-block fences (the R13 killer) — grid.sync provides grid-scope ordering.
// 1024 blocks x 256 thr; LDS = union(dist 34.8KB, row 24.7KB) -> 4 blk/CU =
// exactly 1024 co-resident; __launch_bounds__(256,4) caps VGPR at 128.
// ============================================================================
__global__ __launch_bounds__(256, 4) void mega_kernel(const float* __restrict__ X,
                                                      float* __restrict__ sq,
                                                      ushort* __restrict__ Xbf,
                                                      ushort* __restrict__ distb,
                                                      ushort* __restrict__ Gh,
                                                      float4* __restrict__ part,
                                                      float* __restrict__ out) {
  __shared__ union {
    struct { ushort Als[128 * DSTR]; ushort Bls[128 * DSTR]; } d;
    struct { alignas(16) float sorted[NROW]; alignas(16) int base[BUCKETS]; } r;
  } sm;
  __shared__ float wredf[8];
  __shared__ int wtot[4];
  __shared__ float s_pos[3];
  __shared__ float s_sel[3];
  __shared__ double wsum[4][4];

  cg::grid_group grid = cg::this_grid();
  const int tid = threadIdx.x;
  const int blk = blockIdx.x;
  const int lane = tid & 63, wid = tid >> 6;

  // ---------------- phase 0: prep (4 rows per block, one per wave) ----------
  {
    int i = blk * 4 + wid;
    float2 v = ((const float2*)(X + (size_t)i * NDIM))[lane];
    float s = v.x * v.x + v.y * v.y;
    for (int o = 32; o > 0; o >>= 1) s += __shfl_down(s, o);
    if (lane == 0) sq[i] = s;
    ushort2 h;
    h.x = f2bf(v.x);
    h.y = f2bf(v.y);
    ((ushort2*)(Xbf + (size_t)i * NDIM))[lane] = h;
  }
  grid.sync();

  // ---------------- phase 1: dist tile + gumbel slice (R12 body) ------------
  {
    const int bi = blk >> 5, bj = blk & 31;
    const int q = lane >> 4, ln = lane & 15;
    const ushort* Ag = Xbf + (size_t)bi * 128 * NDIM;
    const ushort* Bg = Xbf + (size_t)bj * 128 * NDIM;

    f32x4 acc[8][2];
#pragma unroll
    for (int mt = 0; mt < 8; ++mt)
#pragma unroll
      for (int nt = 0; nt < 2; ++nt) acc[mt][nt] = (f32x4){0.f, 0.f, 0.f, 0.f};

    for (int kh = 0; kh < 2; ++kh) {
      if (kh) __syncthreads();
#pragma unroll
      for (int t = 0; t < 4; ++t) {
        int c = tid + 256 * t;
        int r = c >> 3, k8 = (c & 7) << 3;
        *(short8*)&sm.d.Als[r * DSTR + k8] =
            *(const short8*)(Ag + (size_t)r * NDIM + kh * 64 + k8);
        *(short8*)&sm.d.Bls[r * DSTR + k8] =
            *(const short8*)(Bg + (size_t)r * NDIM + kh * 64 + k8);
      }
      __syncthreads();
#pragma unroll
      for (int k0 = 0; k0 < 64; k0 += 32) {
        int kf = k0 + q * 8;
        short8 a[8], b[2];
#pragma unroll
        for (int mt = 0; mt < 8; ++mt)
          a[mt] = *(const short8*)&sm.d.Als[(mt * 16 + ln) * DSTR + kf];
#pragma unroll
        for (int nt = 0; nt < 2; ++nt)
          b[nt] = *(const short8*)&sm.d.Bls[(wid * 32 + 2 * ln + nt) * DSTR + kf];
#pragma unroll
        for (int mt = 0; mt < 8; ++mt)
#pragma unroll
          for (int nt = 0; nt < 2; ++nt)
            acc[mt][nt] = __builtin_amdgcn_mfma_f32_16x16x32_bf16(
                a[mt], b[nt], acc[mt][nt], 0, 0, 0);
      }
    }

    const int jcol = bj * 128 + wid * 32 + 2 * ln;
    float sqj0 = sq[jcol], sqj1 = sq[jcol + 1];
#pragma unroll
    for (int mt = 0; mt < 8; ++mt) {
      int ibase = bi * 128 + mt * 16 + q * 4;
#pragma unroll
      for (int r = 0; r < 4; ++r) {
        int i = ibase + r;
        float sqi = sq[i];
        float dx = sqrtf(fmaxf(sqi + sqj0 - 2.0f * acc[mt][0][r], 1e-12f));
        float dy = sqrtf(fmaxf(sqi + sqj1 - 2.0f * acc[mt][1][r], 1e-12f));
        uint32_t pack = ((uint32_t)f2bf(dy) << 16) | (uint32_t)f2bf(dx);
        *(uint32_t*)(distb + (size_t)i * NROW + jcol) = pack;
      }
    }

    if (Gh) {
      uint32_t b0 = (uint32_t)blk * 16368u;
#pragma unroll
      for (int t = 0; t < 16; ++t) {
        int c = tid + 256 * t;
        if (c < 4092) {
          uint32_t f0 = b0 + (uint32_t)c * 4u;
          ushort4 h;
          h.x = f2h(gumbel_ref(f0 + 0u));
          h.y = f2h(gumbel_ref(f0 + 1u));
          h.z = f2h(gumbel_ref(f0 + 2u));
          h.w = f2h(gumbel_ref(f0 + 3u));
          *(ushort4*)(Gh + f0) = h;
        }
      }
    }
  }
  grid.sync();

  // ---------------- phase 2: 4 rows per block (R12 row body) ----------------
  for (int rr = 0; rr < 4; ++rr) {
    const int i = blk * 4 + rr;
    const ushort* row = distb + (size_t)i * NROW;
    const int gbase = i & ~3;
    __syncthreads();   // protect s_pos/s_sel/LDS reuse across row iterations

    {
      int4* b4 = (int4*)sm.r.base;
      b4[tid] = (int4){0, 0, 0, 0};
      b4[tid + 256] = (int4){0, 0, 0, 0};
    }

    ushort cd[16];
    float x[16];
    {
      short8 r0 = *(const short8*)(row + tid * 16);
      short8 r1 = *(const short8*)(row + tid * 16 + 8);
#pragma unroll
      for (int k = 0; k < 8; ++k) {
        cd[k] = (ushort)r0[k];     x[k] = bf2f(cd[k]);
        cd[8 + k] = (ushort)r1[k]; x[8 + k] = bf2f(cd[8 + k]);
      }
    }

    if (tid == (gbase >> 4)) {
      float p[3]; int np = 0;
#pragma unroll
      for (int qq = 0; qq < 4; ++qq) {
        int j = gbase + qq;
        if (j != i) p[np++] = x[j & 15];
      }
      float a = p[0], b = p[1], c = p[2], t_;
      if (a > b) { t_ = a; a = b; b = t_; }
      if (b > c) { t_ = b; b = c; c = t_; }
      if (a > b) { t_ = a; a = b; b = t_; }
      s_pos[0] = a; s_pos[1] = b; s_pos[2] = c;
    }

#pragma unroll
    for (int qq = 0; qq < 16; ++qq) {
      int j = tid * 16 + qq;
      if ((j >> 2) == (i >> 2)) { x[qq] = INF_VAL; cd[qq] = 0x7F80u; }
    }
    __syncthreads();

    int bkt[16];
    int ord[16];
    float ls = 0.f;
#pragma unroll
    for (int qq = 0; qq < 16; ++qq) {
      bkt[qq] = bucket_code(cd[qq]);
      ord[qq] = atomicAdd(&sm.r.base[bkt[qq]], 1);
      if (x[qq] < 1e29f) ls += x[qq];
    }
    for (int o = 32; o > 0; o >>= 1) ls += __shfl_down(ls, o);
    if (lane == 0) wredf[wid] = ls;
    __syncthreads();
    const float negsum = wredf[0] + wredf[1] + wredf[2] + wredf[3];
    const float mean = negsum / (float)KNEG;

    int c8[8]; int lsum = 0;
#pragma unroll
    for (int qq = 0; qq < 8; ++qq) {
      int t_ = sm.r.base[tid * 8 + qq];
      c8[qq] = lsum; lsum += t_;
    }
    float ls2 = 0.f;
#pragma unroll
    for (int qq = 0; qq < 16; ++qq)
      if (x[qq] < 1e29f) { float z = x[qq] - mean; ls2 += z * z; }
    int incl = lsum;
    for (int off = 1; off < 64; off <<= 1) {
      int o = __shfl_up(incl, off);
      if (lane >= off) incl += o;
    }
    for (int o = 32; o > 0; o >>= 1) ls2 += __shfl_down(ls2, o);
    if (lane == 63) wtot[wid] = incl;
    if (lane == 0) wredf[4 + wid] = ls2;
    __syncthreads();
    const float var = (wredf[4] + wredf[5] + wredf[6] + wredf[7]) / (float)KNEG;
    const float stdv = sqrtf(var);
    const float rdenom = __frcp_rn(2.0f * stdv * stdv);
    int excl = incl - lsum;
#pragma unroll
    for (int w = 0; w < 4; ++w) if (w < wid) excl += wtot[w];
#pragma unroll
    for (int qq = 0; qq < 8; ++qq) sm.r.base[tid * 8 + qq] = excl + c8[qq];
    __syncthreads();

#pragma unroll
    for (int qq = 0; qq < 16; ++qq) {
      int p = sm.r.base[bkt[qq]] + ord[qq];
      sm.r.sorted[p] = x[qq];
    }
    __syncthreads();

    float* cscore = (float*)sm.r.base;
    float* cx     = (float*)sm.r.base + 768;
    int*   crank  = (int*)sm.r.sorted;
    float* redf   = sm.r.sorted + 1024;
    int*   redi   = (int*)(sm.r.sorted + 1280);
    int*   redi2  = (int*)(sm.r.sorted + 1536);

    const uint32_t fbase = (uint32_t)i * (uint32_t)KNEG;
    const ushort* grow = Gh ? (Gh + fbase) : nullptr;
    float t0s = -1e38f, t1s = -1e38f, t2s = -1e38f;
    int   t0r = 0x7fffffff, t1r = 0x7fffffff, t2r = 0x7fffffff;
    float t0x = 0.f, t1x = 0.f, t2x = 0.f;
#pragma unroll
    for (int qq = 0; qq < 16; ++qq) {
      int p = tid + 256 * qq;
      float xv = sm.r.sorted[p];
      if (p < KNEG) {
        float z = xv - mean;
        float gv = grow ? h2f(grow[p]) : gumbel_ref(fbase + (uint32_t)p);
        float sv = fmaf(z * z, rdenom, gv);
        if (sv > t2s || (sv == t2s && p < t2r)) {
          t2s = sv; t2r = p; t2x = xv;
          if (t2s > t1s || (t2s == t1s && t2r < t1r)) {
            float ts = t1s; int tr = t1r; float tx = t1x;
            t1s = t2s; t1r = t2r; t1x = t2x; t2s = ts; t2r = tr; t2x = tx;
          }
          if (t1s > t0s || (t1s == t0s && t1r < t0r)) {
            float ts = t0s; int tr = t0r; float tx = t0x;
            t0s = t1s; t0r = t1r; t0x = t1x; t1s = ts; t1r = tr; t1x = tx;
          }
        }
      }
    }
    __syncthreads();

    cscore[tid * 3 + 0] = t0s; crank[tid * 3 + 0] = t0r; cx[tid * 3 + 0] = t0x;
    cscore[tid * 3 + 1] = t1s; crank[tid * 3 + 1] = t1r; cx[tid * 3 + 1] = t1x;
    cscore[tid * 3 + 2] = t2s; crank[tid * 3 + 2] = t2r; cx[tid * 3 + 2] = t2x;
    __syncthreads();

    for (int t = 0; t < 3; ++t) {
      float bs = -1e38f; int br = 0x7fffffff; int bidx = 0;
      for (int k = tid; k < 768; k += 256) {
        float s_ = cscore[k]; int r_ = crank[k];
        if (s_ > bs || (s_ == bs && r_ < br)) { bs = s_; br = r_; bidx = k; }
      }
      redf[tid] = bs; redi[tid] = br; redi2[tid] = bidx;
      __syncthreads();
      if (tid < 64) {
        float s0_ = redf[tid]; int r0_ = redi[tid]; int i0_ = redi2[tid];
#pragma unroll
        for (int o = 64; o < 256; o += 64) {
          float s1 = redf[tid + o]; int r1 = redi[tid + o];
          if (s1 > s0_ || (s1 == s0_ && r1 < r0_)) {
            s0_ = s1; r0_ = r1; i0_ = redi2[tid + o];
          }
        }
        for (int off = 32; off > 0; off >>= 1) {
          float s1 = __shfl_down(s0_, off);
          int r1 = __shfl_down(r0_, off);
          int i1 = __shfl_down(i0_, off);
          if (s1 > s0_ || (s1 == s0_ && r1 < r0_)) { s0_ = s1; r0_ = r1; i0_ = i1; }
        }
        if (tid == 0) { s_sel[t] = cx[i0_]; cscore[i0_] = -1e38f; }
      }
      __syncthreads();
    }

    if (tid == 0) {
      float p0 = s_pos[0], p1 = s_pos[1], p2 = s_pos[2];
      float thr = p2 + 0.05f;
      float samp[3]; bool kept[3]; int cnt = 0;
#pragma unroll
      for (int t = 0; t < 3; ++t) {
        samp[t] = s_sel[t];
        kept[t] = samp[t] < thr;
        cnt += kept[t] ? 1 : 0;
      }
      bool any = cnt > 0;
      float pos_loss = 0.5f *
          (softplus_ref(-2.0f * (1.0f - p0)) + softplus_ref(-2.0f * (1.0f - p1)) +
           softplus_ref(-2.0f * (1.0f - p2))) / 3.0f;
      float nsum = 0.0f;
#pragma unroll
      for (int t = 0; t < 3; ++t)
        if (kept[t]) nsum += softplus_ref(20.0f * (1.0f - samp[t]));
      float neg_loss = 0.05f * nsum / (float)(cnt > 0 ? cnt : 1);
      float row_loss = any ? (pos_loss + neg_loss) : 0.0f;
      int first = kept[0] ? 0 : (kept[1] ? 1 : (kept[2] ? 2 : 0));
      float neg0 = samp[first];
      float errv = (any && (p0 < neg0 - 0.1f)) ? 1.0f : 0.0f;
      float4 pr;
      pr.x = row_loss; pr.y = errv; pr.z = p0 + p1 + p2; pr.w = negsum;
      part[i] = pr;
    }
  }
  grid.sync();

  // ---------------- phase 3: block 0 reduces -> out ----------------
  if (blk == 0) {
    double s0 = 0.0, s1 = 0.0, s2 = 0.0, s3 = 0.0;
    for (int k = tid; k < NROW; k += 256) {
      float4 v = part[k];
      s0 += (double)v.x; s1 += (double)v.y; s2 += (double)v.z; s3 += (double)v.w;
    }
    for (int o = 32; o > 0; o >>= 1) {
      s0 += __shfl_down(s0, o); s1 += __shfl_down(s1, o);
      s2 += __shfl_down(s2, o); s3 += __shfl_down(s3, o);
    }
    if (lane == 0) {
      wsum[wid][0] = s0; wsum[wid][1] = s1; wsum[wid][2] = s2; wsum[wid][3] = s3;
    }
    __syncthreads();
    if (tid == 0) {
      double a0 = wsum[0][0] + wsum[1][0] + wsum[2][0] + wsum[3][0];
      double a1 = wsum[0][1] + wsum[1][1] + wsum[2][1] + wsum[3][1];
      double a2 = wsum[0][2] + wsum[1][2] + wsum[2][2] + wsum[3][2];
      double a3 = wsum[0][3] + wsum[1][3] + wsum[2][3] + wsum[3][3];
      out[0] = (float)(a0 / (double)NROW);
      out[1] = (float)(1.0 - a1 / (double)NROW);
      out[2] = (float)(a2 / ((double)NROW * 3.0));
      out[3] = (float)(a3 / ((double)NROW * (double)KNEG));
    }
  }
}

extern "C" void kernel_launch(void* const* d_in, const int* in_sizes, int n_in,
                              void* d_out, int out_size, void* d_ws, size_t ws_size,
                              hipStream_t stream) {
  (void)in_sizes; (void)n_in; (void)out_size;
  const float* X = (const float*)d_in[0];
  float* out = (float*)d_out;
  char* ws = (char*)d_ws;

  ushort* distb = (ushort*)ws;                                     // 32 MiB bf16
  size_t off = (size_t)NROW * NROW * sizeof(ushort);
  float* sq = (float*)(ws + off);            off += NROW * sizeof(float);
  ushort* Xbf = (ushort*)(ws + off);         off += (size_t)NROW * NDIM * sizeof(ushort);
  float4* part = (float4*)(ws + off);        off += (size_t)NROW * sizeof(float4);
  ushort* Gh = nullptr;
  if (ws_size >= off + GTOT * sizeof(ushort)) Gh = (ushort*)(ws + off);

  const float* Xa = X; float* sqa = sq; ushort* Xbfa = Xbf;
  ushort* distba = distb; ushort* Gha = Gh; float4* parta = part; float* outa = out;
  void* args[] = {&Xa, &sqa, &Xbfa, &distba, &Gha, &parta, &outa};
  hipError_t e = hipLaunchCooperativeKernel((void*)mega_kernel, dim3(DISTBLKS),
                                            dim3(256), args, 0, stream);
  if (e != hipSuccess) {
    (void)hipGetLastError();  // clear; fall back to the known-good R12 pipeline
    prep_kernel<<<NROW, 64, 0, stream>>>(X, sq, Xbf);
    dist_gumbel<<<DISTBLKS, 256, 0, stream>>>(Xbf, sq, distb, Gh);
    row_kernel<<<NROW, 256, 0, stream>>>(distb, Gh, part);
    reduce_kernel<<<1, 256, 0, stream>>>(part, out);
  }
}

// Round 15
// 178.704 us; speedup vs baseline: 2.7087x; 2.7087x over previous
//
#include <hip/hip_runtime.h>
#include <stdint.h>

#define NROW 4096
#define NDIM 128
#define KNEG 4092
#define INF_VAL 1e30f
#define BUCKETS 2048
#define GTOT ((size_t)NROW * (size_t)KNEG)   // 16,760,832 = 1024 * 16368
#define DISTBLKS 1024                         // 32x32 tiles of 128x128
#define DSTR 68

typedef __attribute__((ext_vector_type(8))) short short8;
typedef __attribute__((ext_vector_type(4))) float f32x4;

// ---------------- Threefry-2x32-20, key = (0, 42) ----------------
__device__ __forceinline__ uint32_t rotl32(uint32_t v, int d) {
  return (v << d) | (v >> (32 - d));
}

__device__ __forceinline__ void threefry2x32(uint32_t x0, uint32_t x1,
                                             uint32_t& y0, uint32_t& y1) {
  const uint32_t k0 = 0u, k1 = 42u;
  const uint32_t k2 = 0x1BD11BDAu ^ k0 ^ k1;
  uint32_t v0 = x0 + k0, v1 = x1 + k1;
#define TF_R(r) v0 += v1; v1 = rotl32(v1, r); v1 ^= v0;
  TF_R(13) TF_R(15) TF_R(26) TF_R(6)
  v0 += k1; v1 += k2 + 1u;
  TF_R(17) TF_R(29) TF_R(16) TF_R(24)
  v0 += k2; v1 += k0 + 2u;
  TF_R(13) TF_R(15) TF_R(26) TF_R(6)
  v0 += k0; v1 += k1 + 3u;
  TF_R(17) TF_R(29) TF_R(16) TF_R(24)
  v0 += k1; v1 += k2 + 4u;
  TF_R(13) TF_R(15) TF_R(26) TF_R(6)
  v0 += k2; v1 += k0 + 5u;
#undef TF_R
  y0 = v0; y1 = v1;
}

// partitionable threefry, bits = y1 — verified R1; __logf verified R3
__device__ __forceinline__ float gumbel_ref(uint32_t f) {
  uint32_t y0, y1;
  threefry2x32(0u, f, y0, y1);
  uint32_t m = y1 >> 9;
  float u;
  if (m == 0u) u = 1.17549435e-38f;
  else u = __uint_as_float(m | 0x3f800000u) - 1.0f;
  return -__logf(-__logf(u));
}

__device__ __forceinline__ float softplus_ref(float x) {
  return fmaxf(x, 0.0f) + log1pf(expf(-fabsf(x)));
}

__device__ __forceinline__ ushort f2h(float f) {
  _Float16 h = (_Float16)f;
  return *(ushort*)&h;
}
__device__ __forceinline__ float h2f(ushort u) {
  _Float16 h = *(_Float16*)&u;
  return (float)h;
}
__device__ __forceinline__ float bf2f(ushort u) {
  return __uint_as_float(((uint32_t)u) << 16);
}
__device__ __forceinline__ ushort f2bf(float f) {
  uint32_t u = __float_as_uint(f);
  u += 0x7fffu + ((u >> 16) & 1u);
  return (ushort)(u >> 16);
}

// bucket = bf16 code (monotone & injective for positive floats); every bucket
// holds only exactly-equal values => scatter position IS the exact rank.
__device__ __forceinline__ int bucket_code(ushort code) {
  return min(max((int)code - 0x4000, 0), BUCKETS - 1);
}

// ---------------- kernel A: sumsq + fp32->bf16 convert ----------------
__global__ __launch_bounds__(64) void prep_kernel(const float* __restrict__ X,
                                                  float* __restrict__ sq,
                                                  ushort* __restrict__ Xbf) {
  int i = blockIdx.x;
  int lane = threadIdx.x;
  float2 v = ((const float2*)(X + (size_t)i * NDIM))[lane];
  float s = v.x * v.x + v.y * v.y;
  for (int o = 32; o > 0; o >>= 1) s += __shfl_down(s, o);
  if (lane == 0) sq[i] = s;
  ushort2 h;
  h.x = f2bf(v.x);
  h.y = f2bf(v.y);
  ((ushort2*)(Xbf + (size_t)i * NDIM))[lane] = h;
}

// ---------------- kernel B: dist tile + gumbel slice per block (R12) --------
__global__ __launch_bounds__(256) void dist_gumbel(const ushort* __restrict__ Xbf,
                                                   const float* __restrict__ sq,
                                                   ushort* __restrict__ distb,
                                                   ushort* __restrict__ gh) {
  __shared__ ushort Als[128 * DSTR];
  __shared__ ushort Bls[128 * DSTR];
  const int tid = threadIdx.x;
  const int bi = blockIdx.x >> 5, bj = blockIdx.x & 31;
  const int wave = tid >> 6, lane = tid & 63;
  const int q = lane >> 4, ln = lane & 15;
  const ushort* Ag = Xbf + (size_t)bi * 128 * NDIM;
  const ushort* Bg = Xbf + (size_t)bj * 128 * NDIM;

  f32x4 acc[8][2];
#pragma unroll
  for (int mt = 0; mt < 8; ++mt)
#pragma unroll
    for (int nt = 0; nt < 2; ++nt) acc[mt][nt] = (f32x4){0.f, 0.f, 0.f, 0.f};

  for (int kh = 0; kh < 2; ++kh) {
    if (kh) __syncthreads();
#pragma unroll
    for (int t = 0; t < 4; ++t) {
      int c = tid + 256 * t;
      int r = c >> 3, k8 = (c & 7) << 3;
      *(short8*)&Als[r * DSTR + k8] =
          *(const short8*)(Ag + (size_t)r * NDIM + kh * 64 + k8);
      *(short8*)&Bls[r * DSTR + k8] =
          *(const short8*)(Bg + (size_t)r * NDIM + kh * 64 + k8);
    }
    __syncthreads();
#pragma unroll
    for (int k0 = 0; k0 < 64; k0 += 32) {
      int kf = k0 + q * 8;
      short8 a[8], b[2];
#pragma unroll
      for (int mt = 0; mt < 8; ++mt)
        a[mt] = *(const short8*)&Als[(mt * 16 + ln) * DSTR + kf];
      // lane owns ADJACENT cols 2*ln, 2*ln+1 -> packed bf16x2 dword stores
#pragma unroll
      for (int nt = 0; nt < 2; ++nt)
        b[nt] = *(const short8*)&Bls[(wave * 32 + 2 * ln + nt) * DSTR + kf];
#pragma unroll
      for (int mt = 0; mt < 8; ++mt)
#pragma unroll
        for (int nt = 0; nt < 2; ++nt)
          acc[mt][nt] = __builtin_amdgcn_mfma_f32_16x16x32_bf16(
              a[mt], b[nt], acc[mt][nt], 0, 0, 0);
    }
  }

  const int jcol = bj * 128 + wave * 32 + 2 * ln;
  float sqj0 = sq[jcol], sqj1 = sq[jcol + 1];
#pragma unroll
  for (int mt = 0; mt < 8; ++mt) {
    int ibase = bi * 128 + mt * 16 + q * 4;
#pragma unroll
    for (int r = 0; r < 4; ++r) {
      int i = ibase + r;
      float sqi = sq[i];
      float dx = sqrtf(fmaxf(sqi + sqj0 - 2.0f * acc[mt][0][r], 1e-12f));
      float dy = sqrtf(fmaxf(sqi + sqj1 - 2.0f * acc[mt][1][r], 1e-12f));
      uint32_t pack = ((uint32_t)f2bf(dy) << 16) | (uint32_t)f2bf(dx);
      *(uint32_t*)(distb + (size_t)i * NROW + jcol) = pack;
    }
  }

  if (gh) {
    uint32_t b0 = (uint32_t)blockIdx.x * 16368u;
#pragma unroll
    for (int t = 0; t < 16; ++t) {
      int c = tid + 256 * t;
      if (c < 4092) {
        uint32_t f0 = b0 + (uint32_t)c * 4u;
        ushort4 h;
        h.x = f2h(gumbel_ref(f0 + 0u));
        h.y = f2h(gumbel_ref(f0 + 1u));
        h.z = f2h(gumbel_ref(f0 + 2u));
        h.w = f2h(gumbel_ref(f0 + 3u));
        *(ushort4*)(gh + f0) = h;
      }
    }
  }
}

// ---------------- kernel C: per-row rank + sample + loss ----------------
// R12 body with two changes: (1) scatter array holds bf16 CODES (8 KB, not
// 16 KB) -> LDS ~16.5 KB -> 8 blocks/CU (was 6) for latency hiding; value is
// recovered by a 1-op shift, ranks/ties unchanged. (2) the 16 G-table loads
// are prefetched into registers before the selection loop.
__global__ __launch_bounds__(256) void row_kernel(const ushort* __restrict__ distb,
                                                  const ushort* __restrict__ Gh,
                                                  float4* __restrict__ part) {
  __shared__ alignas(16) ushort sortc[NROW];   // 8 KB (bf16 codes, rank-ordered)
  __shared__ alignas(16) int base[BUCKETS];    // 8 KB (bucket STARTs)
  __shared__ float wredf[8];
  __shared__ int wtot[4];
  __shared__ float s_pos[3];
  __shared__ float s_sel[3];

  // aliases — live only after the score pass (barrier-separated)
  float* cscore = (float*)base;                      // 768 (3 KB of base's 8 KB)
  float* cx     = (float*)base + 768;                // 768 (3 KB)
  int*   crank  = (int*)sortc;                       // 768 (3 KB of sortc's 8 KB)
  float* redf   = (float*)((char*)sortc + 3072);     // 256 (1 KB)
  int*   redi   = (int*)((char*)sortc + 4096);       // 256 (1 KB)
  int*   redi2  = (int*)((char*)sortc + 5120);       // 256 (1 KB)

  const int i = blockIdx.x;
  const int tid = threadIdx.x;
  const int lane = tid & 63, wid = tid >> 6;
  const ushort* row = distb + (size_t)i * NROW;
  const int gbase = i & ~3;

  {
    int4* b4 = (int4*)base;
    b4[tid] = (int4){0, 0, 0, 0};
    b4[tid + 256] = (int4){0, 0, 0, 0};
  }

  ushort cd[16];
  float x[16];
  {
    short8 r0 = *(const short8*)(row + tid * 16);
    short8 r1 = *(const short8*)(row + tid * 16 + 8);
#pragma unroll
    for (int k = 0; k < 8; ++k) {
      cd[k] = (ushort)r0[k];     x[k] = bf2f(cd[k]);
      cd[8 + k] = (ushort)r1[k]; x[8 + k] = bf2f(cd[8 + k]);
    }
  }

  if (tid == (gbase >> 4)) {
    float p[3]; int np = 0;
#pragma unroll
    for (int qq = 0; qq < 4; ++qq) {
      int j = gbase + qq;
      if (j != i) p[np++] = x[j & 15];
    }
    float a = p[0], b = p[1], c = p[2], t_;
    if (a > b) { t_ = a; a = b; b = t_; }
    if (b > c) { t_ = b; b = c; c = t_; }
    if (a > b) { t_ = a; a = b; b = t_; }
    s_pos[0] = a; s_pos[1] = b; s_pos[2] = c;
  }

#pragma unroll
  for (int qq = 0; qq < 16; ++qq) {
    int j = tid * 16 + qq;
    if ((j >> 2) == (i >> 2)) { x[qq] = INF_VAL; cd[qq] = 0x7F80u; }
  }
  __syncthreads();

  int bkt[16];
  int ord[16];
  float ls = 0.f;
#pragma unroll
  for (int qq = 0; qq < 16; ++qq) {
    bkt[qq] = bucket_code(cd[qq]);
    ord[qq] = atomicAdd(&base[bkt[qq]], 1);
    if (x[qq] < 1e29f) ls += x[qq];
  }
  for (int o = 32; o > 0; o >>= 1) ls += __shfl_down(ls, o);
  if (lane == 0) wredf[wid] = ls;
  __syncthreads();
  const float negsum = wredf[0] + wredf[1] + wredf[2] + wredf[3];
  const float mean = negsum / (float)KNEG;

  int c8[8]; int lsum = 0;
#pragma unroll
  for (int qq = 0; qq < 8; ++qq) {
    int t_ = base[tid * 8 + qq];
    c8[qq] = lsum; lsum += t_;
  }
  float ls2 = 0.f;
#pragma unroll
  for (int qq = 0; qq < 16; ++qq)
    if (x[qq] < 1e29f) { float z = x[qq] - mean; ls2 += z * z; }
  int incl = lsum;
  for (int off = 1; off < 64; off <<= 1) {
    int o = __shfl_up(incl, off);
    if (lane >= off) incl += o;
  }
  for (int o = 32; o > 0; o >>= 1) ls2 += __shfl_down(ls2, o);
  if (lane == 63) wtot[wid] = incl;
  if (lane == 0) wredf[4 + wid] = ls2;
  __syncthreads();
  const float var = (wredf[4] + wredf[5] + wredf[6] + wredf[7]) / (float)KNEG;
  const float stdv = sqrtf(var);
  const float rdenom = __frcp_rn(2.0f * stdv * stdv);
  int excl = incl - lsum;
#pragma unroll
  for (int w = 0; w < 4; ++w) if (w < wid) excl += wtot[w];
#pragma unroll
  for (int qq = 0; qq < 8; ++qq) base[tid * 8 + qq] = excl + c8[qq];
  __syncthreads();

  // ---- place CODES: pos = start + ordinal (EXACT rank) ----
#pragma unroll
  for (int qq = 0; qq < 16; ++qq) {
    int p = base[bkt[qq]] + ord[qq];
    sortc[p] = cd[qq];
  }
  __syncthreads();

  // ---- prefetch G (16 independent coalesced loads, rank = p) ----
  const uint32_t fbase = (uint32_t)i * (uint32_t)KNEG;
  const ushort* grow = Gh ? (Gh + fbase) : nullptr;
  ushort gcode[16];
  if (grow) {
#pragma unroll
    for (int qq = 0; qq < 16; ++qq) gcode[qq] = grow[tid + 256 * qq];
  }

  // ---- score/top-3: rank = p, loop-free ----
  float t0s = -1e38f, t1s = -1e38f, t2s = -1e38f;
  int   t0r = 0x7fffffff, t1r = 0x7fffffff, t2r = 0x7fffffff;
  float t0x = 0.f, t1x = 0.f, t2x = 0.f;
#pragma unroll
  for (int qq = 0; qq < 16; ++qq) {
    int p = tid + 256 * qq;
    float xv = bf2f(sortc[p]);
    if (p < KNEG) {
      float z = xv - mean;
      float gv = grow ? h2f(gcode[qq]) : gumbel_ref(fbase + (uint32_t)p);
      float sv = fmaf(z * z, rdenom, gv);
      if (sv > t2s || (sv == t2s && p < t2r)) {
        t2s = sv; t2r = p; t2x = xv;
        if (t2s > t1s || (t2s == t1s && t2r < t1r)) {
          float ts = t1s; int tr = t1r; float tx = t1x;
          t1s = t2s; t1r = t2r; t1x = t2x; t2s = ts; t2r = tr; t2x = tx;
        }
        if (t1s > t0s || (t1s == t0s && t1r < t0r)) {
          float ts = t0s; int tr = t0r; float tx = t0x;
          t0s = t1s; t0r = t1r; t0x = t1x; t1s = ts; t1r = tr; t1x = tx;
        }
      }
    }
  }
  __syncthreads();  // sortc/base reads done; aliases become live

  cscore[tid * 3 + 0] = t0s; crank[tid * 3 + 0] = t0r; cx[tid * 3 + 0] = t0x;
  cscore[tid * 3 + 1] = t1s; crank[tid * 3 + 1] = t1r; cx[tid * 3 + 1] = t1x;
  cscore[tid * 3 + 2] = t2s; crank[tid * 3 + 2] = t2r; cx[tid * 3 + 2] = t2x;
  __syncthreads();

  for (int t = 0; t < 3; ++t) {
    float bs = -1e38f; int br = 0x7fffffff; int bidx = 0;
    for (int k = tid; k < 768; k += 256) {
      float s_ = cscore[k]; int r_ = crank[k];
      if (s_ > bs || (s_ == bs && r_ < br)) { bs = s_; br = r_; bidx = k; }
    }
    redf[tid] = bs; redi[tid] = br; redi2[tid] = bidx;
    __syncthreads();
    if (tid < 64) {
      float s0_ = redf[tid]; int r0_ = redi[tid]; int i0_ = redi2[tid];
#pragma unroll
      for (int o = 64; o < 256; o += 64) {
        float s1 = redf[tid + o]; int r1 = redi[tid + o];
        if (s1 > s0_ || (s1 == s0_ && r1 < r0_)) {
          s0_ = s1; r0_ = r1; i0_ = redi2[tid + o];
        }
      }
      for (int off = 32; off > 0; off >>= 1) {
        float s1 = __shfl_down(s0_, off);
        int r1 = __shfl_down(r0_, off);
        int i1 = __shfl_down(i0_, off);
        if (s1 > s0_ || (s1 == s0_ && r1 < r0_)) { s0_ = s1; r0_ = r1; i0_ = i1; }
      }
      if (tid == 0) { s_sel[t] = cx[i0_]; cscore[i0_] = -1e38f; }
    }
    __syncthreads();
  }

  if (tid == 0) {
    float p0 = s_pos[0], p1 = s_pos[1], p2 = s_pos[2];
    float thr = p2 + 0.05f;
    float samp[3]; bool kept[3]; int cnt = 0;
#pragma unroll
    for (int t = 0; t < 3; ++t) {
      samp[t] = s_sel[t];
      kept[t] = samp[t] < thr;
      cnt += kept[t] ? 1 : 0;
    }
    bool any = cnt > 0;
    float pos_loss = 0.5f *
        (softplus_ref(-2.0f * (1.0f - p0)) + softplus_ref(-2.0f * (1.0f - p1)) +
         softplus_ref(-2.0f * (1.0f - p2))) / 3.0f;
    float nsum = 0.0f;
#pragma unroll
    for (int t = 0; t < 3; ++t)
      if (kept[t]) nsum += softplus_ref(20.0f * (1.0f - samp[t]));
    float neg_loss = 0.05f * nsum / (float)(cnt > 0 ? cnt : 1);
    float row_loss = any ? (pos_loss + neg_loss) : 0.0f;
    int first = kept[0] ? 0 : (kept[1] ? 1 : (kept[2] ? 2 : 0));
    float neg0 = samp[first];
    float errv = (any && (p0 < neg0 - 0.1f)) ? 1.0f : 0.0f;
    float4 pr;
    pr.x = row_loss; pr.y = errv; pr.z = p0 + p1 + p2; pr.w = negsum;
    part[i] = pr;
  }
}

// ---------------- reduce: 4096 float4 partials -> 4 outputs ----------------
__global__ __launch_bounds__(256) void reduce_kernel(const float4* __restrict__ part,
                                                     float* __restrict__ out) {
  __shared__ double wsum[4][4];
  const int tid = threadIdx.x;
  const int lane = tid & 63, wid = tid >> 6;
  double s0 = 0.0, s1 = 0.0, s2 = 0.0, s3 = 0.0;
  for (int k = tid; k < NROW; k += 256) {
    float4 v = part[k];
    s0 += (double)v.x; s1 += (double)v.y; s2 += (double)v.z; s3 += (double)v.w;
  }
  for (int o = 32; o > 0; o >>= 1) {
    s0 += __shfl_down(s0, o); s1 += __shfl_down(s1, o);
    s2 += __shfl_down(s2, o); s3 += __shfl_down(s3, o);
  }
  if (lane == 0) {
    wsum[wid][0] = s0; wsum[wid][1] = s1; wsum[wid][2] = s2; wsum[wid][3] = s3;
  }
  __syncthreads();
  if (tid == 0) {
    double a0 = wsum[0][0] + wsum[1][0] + wsum[2][0] + wsum[3][0];
    double a1 = wsum[0][1] + wsum[1][1] + wsum[2][1] + wsum[3][1];
    double a2 = wsum[0][2] + wsum[1][2] + wsum[2][2] + wsum[3][2];
    double a3 = wsum[0][3] + wsum[1][3] + wsum[2][3] + wsum[3][3];
    out[0] = (float)(a0 / (double)NROW);
    out[1] = (float)(1.0 - a1 / (double)NROW);
    out[2] = (float)(a2 / ((double)NROW * 3.0));
    out[3] = (float)(a3 / ((double)NROW * (double)KNEG));
  }
}

extern "C" void kernel_launch(void* const* d_in, const int* in_sizes, int n_in,
                              void* d_out, int out_size, void* d_ws, size_t ws_size,
                              hipStream_t stream) {
  (void)in_sizes; (void)n_in; (void)out_size;
  const float* X = (const float*)d_in[0];
  float* out = (float*)d_out;
  char* ws = (char*)d_ws;

  ushort* distb = (ushort*)ws;                                     // 32 MiB bf16
  size_t off = (size_t)NROW * NROW * sizeof(ushort);
  float* sq = (float*)(ws + off);            off += NROW * sizeof(float);
  ushort* Xbf = (ushort*)(ws + off);         off += (size_t)NROW * NDIM * sizeof(ushort);
  float4* part = (float4*)(ws + off);        off += (size_t)NROW * sizeof(float4);
  // fp16 Gumbel table (32 MB) — only if workspace allows; else inline fallback
  ushort* Gh = nullptr;
  if (ws_size >= off + GTOT * sizeof(ushort)) Gh = (ushort*)(ws + off);

  prep_kernel<<<NROW, 64, 0, stream>>>(X, sq, Xbf);
  dist_gumbel<<<DISTBLKS, 256, 0, stream>>>(Xbf, sq, distb, Gh);
  row_kernel<<<NROW, 256, 0, stream>>>(distb, Gh, part);
  reduce_kernel<<<1, 256, 0, stream>>>(part, out);
}

// Round 16
// 170.688 us; speedup vs baseline: 2.8359x; 1.0470x over previous
//
#include <hip/hip_runtime.h>
#include <stdint.h>

#define NROW 4096
#define NDIM 128
#define KNEG 4092
#define INF_VAL 1e30f
#define BUCKETS 2048
#define GTOT ((size_t)NROW * (size_t)KNEG)   // 16,760,832 = 1024 * 16368
#define DISTBLKS 1024                         // 32x32 tiles of 128x128
#define DSTR 68

typedef __attribute__((ext_vector_type(8))) short short8;
typedef __attribute__((ext_vector_type(4))) float f32x4;

// ---------------- Threefry-2x32-20, key = (0, 42) ----------------
// __builtin_rotateleft32 -> guaranteed single v_alignbit_b32 per rotate
__device__ __forceinline__ uint32_t rotl32(uint32_t v, int d) {
  return __builtin_rotateleft32(v, (unsigned)d);
}

__device__ __forceinline__ void threefry2x32(uint32_t x0, uint32_t x1,
                                             uint32_t& y0, uint32_t& y1) {
  const uint32_t k0 = 0u, k1 = 42u;
  const uint32_t k2 = 0x1BD11BDAu ^ k0 ^ k1;
  uint32_t v0 = x0 + k0, v1 = x1 + k1;
#define TF_R(r) v0 += v1; v1 = rotl32(v1, r); v1 ^= v0;
  TF_R(13) TF_R(15) TF_R(26) TF_R(6)
  v0 += k1; v1 += k2 + 1u;
  TF_R(17) TF_R(29) TF_R(16) TF_R(24)
  v0 += k2; v1 += k0 + 2u;
  TF_R(13) TF_R(15) TF_R(26) TF_R(6)
  v0 += k0; v1 += k1 + 3u;
  TF_R(17) TF_R(29) TF_R(16) TF_R(24)
  v0 += k1; v1 += k2 + 4u;
  TF_R(13) TF_R(15) TF_R(26) TF_R(6)
  v0 += k2; v1 += k0 + 5u;
#undef TF_R
  y0 = v0; y1 = v1;
}

// partitionable threefry, bits = y1 — verified R1.
// u = m*2^-23 EXACTLY, and v_log_f32 normalizes the exponent, so
// log2(u) == log2((float)m) - 23. One cvt + two v_log_f32:
//   -log(u) = ln2*(23 - log2(m));  g = -ln2*log2(-log(u))
// m==0: reference clamps u to f32-tiny -> -log(u) = 87.33655.
__device__ __forceinline__ float gumbel_ref(uint32_t f) {
  uint32_t y0, y1;
  threefry2x32(0u, f, y0, y1);
  uint32_t m = y1 >> 9;
  float fm = (float)m;                                     // exact (m < 2^24)
  float nl = fmaf(-0.69314718f, __log2f(fm), 15.942385f);  // ln2*(23-log2 m)
  if (m == 0u) nl = 87.33655f;                             // -log(tiny)
  return -0.69314718f * __log2f(nl);
}

__device__ __forceinline__ float softplus_ref(float x) {
  return fmaxf(x, 0.0f) + log1pf(expf(-fabsf(x)));
}

__device__ __forceinline__ ushort f2h(float f) {
  _Float16 h = (_Float16)f;
  return *(ushort*)&h;
}
__device__ __forceinline__ float h2f(ushort u) {
  _Float16 h = *(_Float16*)&u;
  return (float)h;
}
__device__ __forceinline__ float bf2f(ushort u) {
  return __uint_as_float(((uint32_t)u) << 16);
}
__device__ __forceinline__ ushort f2bf(float f) {
  uint32_t u = __float_as_uint(f);
  u += 0x7fffu + ((u >> 16) & 1u);
  return (ushort)(u >> 16);
}

// bucket = bf16 code (monotone & injective for positive floats); every bucket
// holds only exactly-equal values => scatter position IS the exact rank.
__device__ __forceinline__ int bucket_code(ushort code) {
  return min(max((int)code - 0x4000, 0), BUCKETS - 1);
}

// ---------------- kernel A: sumsq + fp32->bf16 convert ----------------
__global__ __launch_bounds__(64) void prep_kernel(const float* __restrict__ X,
                                                  float* __restrict__ sq,
                                                  ushort* __restrict__ Xbf) {
  int i = blockIdx.x;
  int lane = threadIdx.x;
  float2 v = ((const float2*)(X + (size_t)i * NDIM))[lane];
  float s = v.x * v.x + v.y * v.y;
  for (int o = 32; o > 0; o >>= 1) s += __shfl_down(s, o);
  if (lane == 0) sq[i] = s;
  ushort2 h;
  h.x = f2bf(v.x);
  h.y = f2bf(v.y);
  ((ushort2*)(Xbf + (size_t)i * NDIM))[lane] = h;
}

// ---------------- kernel B: dist tile + gumbel slice per block --------------
__global__ __launch_bounds__(256) void dist_gumbel(const ushort* __restrict__ Xbf,
                                                   const float* __restrict__ sq,
                                                   ushort* __restrict__ distb,
                                                   ushort* __restrict__ gh) {
  __shared__ ushort Als[128 * DSTR];
  __shared__ ushort Bls[128 * DSTR];
  const int tid = threadIdx.x;
  const int bi = blockIdx.x >> 5, bj = blockIdx.x & 31;
  const int wave = tid >> 6, lane = tid & 63;
  const int q = lane >> 4, ln = lane & 15;
  const ushort* Ag = Xbf + (size_t)bi * 128 * NDIM;
  const ushort* Bg = Xbf + (size_t)bj * 128 * NDIM;

  f32x4 acc[8][2];
#pragma unroll
  for (int mt = 0; mt < 8; ++mt)
#pragma unroll
    for (int nt = 0; nt < 2; ++nt) acc[mt][nt] = (f32x4){0.f, 0.f, 0.f, 0.f};

  for (int kh = 0; kh < 2; ++kh) {
    if (kh) __syncthreads();
#pragma unroll
    for (int t = 0; t < 4; ++t) {
      int c = tid + 256 * t;
      int r = c >> 3, k8 = (c & 7) << 3;
      *(short8*)&Als[r * DSTR + k8] =
          *(const short8*)(Ag + (size_t)r * NDIM + kh * 64 + k8);
      *(short8*)&Bls[r * DSTR + k8] =
          *(const short8*)(Bg + (size_t)r * NDIM + kh * 64 + k8);
    }
    __syncthreads();
#pragma unroll
    for (int k0 = 0; k0 < 64; k0 += 32) {
      int kf = k0 + q * 8;
      short8 a[8], b[2];
#pragma unroll
      for (int mt = 0; mt < 8; ++mt)
        a[mt] = *(const short8*)&Als[(mt * 16 + ln) * DSTR + kf];
      // lane owns ADJACENT cols 2*ln, 2*ln+1 -> packed bf16x2 dword stores
#pragma unroll
      for (int nt = 0; nt < 2; ++nt)
        b[nt] = *(const short8*)&Bls[(wave * 32 + 2 * ln + nt) * DSTR + kf];
#pragma unroll
      for (int mt = 0; mt < 8; ++mt)
#pragma unroll
        for (int nt = 0; nt < 2; ++nt)
          acc[mt][nt] = __builtin_amdgcn_mfma_f32_16x16x32_bf16(
              a[mt], b[nt], acc[mt][nt], 0, 0, 0);
    }
  }

  const int jcol = bj * 128 + wave * 32 + 2 * ln;
  float sqj0 = sq[jcol], sqj1 = sq[jcol + 1];
#pragma unroll
  for (int mt = 0; mt < 8; ++mt) {
    int ibase = bi * 128 + mt * 16 + q * 4;
#pragma unroll
    for (int r = 0; r < 4; ++r) {
      int i = ibase + r;
      float sqi = sq[i];
      float dx = sqrtf(fmaxf(sqi + sqj0 - 2.0f * acc[mt][0][r], 1e-12f));
      float dy = sqrtf(fmaxf(sqi + sqj1 - 2.0f * acc[mt][1][r], 1e-12f));
      uint32_t pack = ((uint32_t)f2bf(dy) << 16) | (uint32_t)f2bf(dx);
      *(uint32_t*)(distb + (size_t)i * NROW + jcol) = pack;
    }
  }

  if (gh) {
    uint32_t b0 = (uint32_t)blockIdx.x * 16368u;
#pragma unroll
    for (int t = 0; t < 16; ++t) {
      int c = tid + 256 * t;
      if (c < 4092) {
        uint32_t f0 = b0 + (uint32_t)c * 4u;
        ushort4 h;
        h.x = f2h(gumbel_ref(f0 + 0u));
        h.y = f2h(gumbel_ref(f0 + 1u));
        h.z = f2h(gumbel_ref(f0 + 2u));
        h.w = f2h(gumbel_ref(f0 + 3u));
        *(ushort4*)(gh + f0) = h;
      }
    }
  }
}

// ---------------- kernel C: per-row rank + sample + loss (R15) --------------
__global__ __launch_bounds__(256) void row_kernel(const ushort* __restrict__ distb,
                                                  const ushort* __restrict__ Gh,
                                                  float4* __restrict__ part) {
  __shared__ alignas(16) ushort sortc[NROW];   // 8 KB (bf16 codes, rank-ordered)
  __shared__ alignas(16) int base[BUCKETS];    // 8 KB (bucket STARTs)
  __shared__ float wredf[8];
  __shared__ int wtot[4];
  __shared__ float s_pos[3];
  __shared__ float s_sel[3];

  // aliases — live only after the score pass (barrier-separated)
  float* cscore = (float*)base;                      // 768
  float* cx     = (float*)base + 768;                // 768
  int*   crank  = (int*)sortc;                       // 768
  float* redf   = (float*)((char*)sortc + 3072);     // 256
  int*   redi   = (int*)((char*)sortc + 4096);       // 256
  int*   redi2  = (int*)((char*)sortc + 5120);       // 256

  const int i = blockIdx.x;
  const int tid = threadIdx.x;
  const int lane = tid & 63, wid = tid >> 6;
  const ushort* row = distb + (size_t)i * NROW;
  const int gbase = i & ~3;

  {
    int4* b4 = (int4*)base;
    b4[tid] = (int4){0, 0, 0, 0};
    b4[tid + 256] = (int4){0, 0, 0, 0};
  }

  ushort cd[16];
  float x[16];
  {
    short8 r0 = *(const short8*)(row + tid * 16);
    short8 r1 = *(const short8*)(row + tid * 16 + 8);
#pragma unroll
    for (int k = 0; k < 8; ++k) {
      cd[k] = (ushort)r0[k];     x[k] = bf2f(cd[k]);
      cd[8 + k] = (ushort)r1[k]; x[8 + k] = bf2f(cd[8 + k]);
    }
  }

  if (tid == (gbase >> 4)) {
    float p[3]; int np = 0;
#pragma unroll
    for (int qq = 0; qq < 4; ++qq) {
      int j = gbase + qq;
      if (j != i) p[np++] = x[j & 15];
    }
    float a = p[0], b = p[1], c = p[2], t_;
    if (a > b) { t_ = a; a = b; b = t_; }
    if (b > c) { t_ = b; b = c; c = t_; }
    if (a > b) { t_ = a; a = b; b = t_; }
    s_pos[0] = a; s_pos[1] = b; s_pos[2] = c;
  }

#pragma unroll
  for (int qq = 0; qq < 16; ++qq) {
    int j = tid * 16 + qq;
    if ((j >> 2) == (i >> 2)) { x[qq] = INF_VAL; cd[qq] = 0x7F80u; }
  }
  __syncthreads();

  int bkt[16];
  int ord[16];
  float ls = 0.f;
#pragma unroll
  for (int qq = 0; qq < 16; ++qq) {
    bkt[qq] = bucket_code(cd[qq]);
    ord[qq] = atomicAdd(&base[bkt[qq]], 1);
    if (x[qq] < 1e29f) ls += x[qq];
  }
  for (int o = 32; o > 0; o >>= 1) ls += __shfl_down(ls, o);
  if (lane == 0) wredf[wid] = ls;
  __syncthreads();
  const float negsum = wredf[0] + wredf[1] + wredf[2] + wredf[3];
  const float mean = negsum / (float)KNEG;

  int c8[8]; int lsum = 0;
#pragma unroll
  for (int qq = 0; qq < 8; ++qq) {
    int t_ = base[tid * 8 + qq];
    c8[qq] = lsum; lsum += t_;
  }
  float ls2 = 0.f;
#pragma unroll
  for (int qq = 0; qq < 16; ++qq)
    if (x[qq] < 1e29f) { float z = x[qq] - mean; ls2 += z * z; }
  int incl = lsum;
  for (int off = 1; off < 64; off <<= 1) {
    int o = __shfl_up(incl, off);
    if (lane >= off) incl += o;
  }
  for (int o = 32; o > 0; o >>= 1) ls2 += __shfl_down(ls2, o);
  if (lane == 63) wtot[wid] = incl;
  if (lane == 0) wredf[4 + wid] = ls2;
  __syncthreads();
  const float var = (wredf[4] + wredf[5] + wredf[6] + wredf[7]) / (float)KNEG;
  const float stdv = sqrtf(var);
  const float rdenom = __frcp_rn(2.0f * stdv * stdv);
  int excl = incl - lsum;
#pragma unroll
  for (int w = 0; w < 4; ++w) if (w < wid) excl += wtot[w];
#pragma unroll
  for (int qq = 0; qq < 8; ++qq) base[tid * 8 + qq] = excl + c8[qq];
  __syncthreads();

  // ---- place CODES: pos = start + ordinal (EXACT rank) ----
#pragma unroll
  for (int qq = 0; qq < 16; ++qq) {
    int p = base[bkt[qq]] + ord[qq];
    sortc[p] = cd[qq];
  }
  __syncthreads();

  // ---- prefetch G (16 independent coalesced loads, rank = p) ----
  const uint32_t fbase = (uint32_t)i * (uint32_t)KNEG;
  const ushort* grow = Gh ? (Gh + fbase) : nullptr;
  ushort gcode[16];
  if (grow) {
#pragma unroll
    for (int qq = 0; qq < 16; ++qq) gcode[qq] = grow[tid + 256 * qq];
  }

  // ---- score/top-3: rank = p, loop-free ----
  float t0s = -1e38f, t1s = -1e38f, t2s = -1e38f;
  int   t0r = 0x7fffffff, t1r = 0x7fffffff, t2r = 0x7fffffff;
  float t0x = 0.f, t1x = 0.f, t2x = 0.f;
#pragma unroll
  for (int qq = 0; qq < 16; ++qq) {
    int p = tid + 256 * qq;
    float xv = bf2f(sortc[p]);
    if (p < KNEG) {
      float z = xv - mean;
      float gv = grow ? h2f(gcode[qq]) : gumbel_ref(fbase + (uint32_t)p);
      float sv = fmaf(z * z, rdenom, gv);
      if (sv > t2s || (sv == t2s && p < t2r)) {
        t2s = sv; t2r = p; t2x = xv;
        if (t2s > t1s || (t2s == t1s && t2r < t1r)) {
          float ts = t1s; int tr = t1r; float tx = t1x;
          t1s = t2s; t1r = t2r; t1x = t2x; t2s = ts; t2r = tr; t2x = tx;
        }
        if (t1s > t0s || (t1s == t0s && t1r < t0r)) {
          float ts = t0s; int tr = t0r; float tx = t0x;
          t0s = t1s; t0r = t1r; t0x = t1x; t1s = ts; t1r = tr; t1x = tx;
        }
      }
    }
  }
  __syncthreads();  // sortc/base reads done; aliases become live

  cscore[tid * 3 + 0] = t0s; crank[tid * 3 + 0] = t0r; cx[tid * 3 + 0] = t0x;
  cscore[tid * 3 + 1] = t1s; crank[tid * 3 + 1] = t1r; cx[tid * 3 + 1] = t1x;
  cscore[tid * 3 + 2] = t2s; crank[tid * 3 + 2] = t2r; cx[tid * 3 + 2] = t2x;
  __syncthreads();

  for (int t = 0; t < 3; ++t) {
    float bs = -1e38f; int br = 0x7fffffff; int bidx = 0;
    for (int k = tid; k < 768; k += 256) {
      float s_ = cscore[k]; int r_ = crank[k];
      if (s_ > bs || (s_ == bs && r_ < br)) { bs = s_; br = r_; bidx = k; }
    }
    redf[tid] = bs; redi[tid] = br; redi2[tid] = bidx;
    __syncthreads();
    if (tid < 64) {
      float s0_ = redf[tid]; int r0_ = redi[tid]; int i0_ = redi2[tid];
#pragma unroll
      for (int o = 64; o < 256; o += 64) {
        float s1 = redf[tid + o]; int r1 = redi[tid + o];
        if (s1 > s0_ || (s1 == s0_ && r1 < r0_)) {
          s0_ = s1; r0_ = r1; i0_ = redi2[tid + o];
        }
      }
      for (int off = 32; off > 0; off >>= 1) {
        float s1 = __shfl_down(s0_, off);
        int r1 = __shfl_down(r0_, off);
        int i1 = __shfl_down(i0_, off);
        if (s1 > s0_ || (s1 == s0_ && r1 < r0_)) { s0_ = s1; r0_ = r1; i0_ = i1; }
      }
      if (tid == 0) { s_sel[t] = cx[i0_]; cscore[i0_] = -1e38f; }
    }
    __syncthreads();
  }

  if (tid == 0) {
    float p0 = s_pos[0], p1 = s_pos[1], p2 = s_pos[2];
    float thr = p2 + 0.05f;
    float samp[3]; bool kept[3]; int cnt = 0;
#pragma unroll
    for (int t = 0; t < 3; ++t) {
      samp[t] = s_sel[t];
      kept[t] = samp[t] < thr;
      cnt += kept[t] ? 1 : 0;
    }
    bool any = cnt > 0;
    float pos_loss = 0.5f *
        (softplus_ref(-2.0f * (1.0f - p0)) + softplus_ref(-2.0f * (1.0f - p1)) +
         softplus_ref(-2.0f * (1.0f - p2))) / 3.0f;
    float nsum = 0.0f;
#pragma unroll
    for (int t = 0; t < 3; ++t)
      if (kept[t]) nsum += softplus_ref(20.0f * (1.0f - samp[t]));
    float neg_loss = 0.05f * nsum / (float)(cnt > 0 ? cnt : 1);
    float row_loss = any ? (pos_loss + neg_loss) : 0.0f;
    int first = kept[0] ? 0 : (kept[1] ? 1 : (kept[2] ? 2 : 0));
    float neg0 = samp[first];
    float errv = (any && (p0 < neg0 - 0.1f)) ? 1.0f : 0.0f;
    float4 pr;
    pr.x = row_loss; pr.y = errv; pr.z = p0 + p1 + p2; pr.w = negsum;
    part[i] = pr;
  }
}

// ---------------- reduce: 4096 float4 partials -> 4 outputs ----------------
__global__ __launch_bounds__(256) void reduce_kernel(const float4* __restrict__ part,
                                                     float* __restrict__ out) {
  __shared__ double wsum[4][4];
  const int tid = threadIdx.x;
  const int lane = tid & 63, wid = tid >> 6;
  double s0 = 0.0, s1 = 0.0, s2 = 0.0, s3 = 0.0;
  for (int k = tid; k < NROW; k += 256) {
    float4 v = part[k];
    s0 += (double)v.x; s1 += (double)v.y; s2 += (double)v.z; s3 += (double)v.w;
  }
  for (int o = 32; o > 0; o >>= 1) {
    s0 += __shfl_down(s0, o); s1 += __shfl_down(s1, o);
    s2 += __shfl_down(s2, o); s3 += __shfl_down(s3, o);
  }
  if (lane == 0) {
    wsum[wid][0] = s0; wsum[wid][1] = s1; wsum[wid][2] = s2; wsum[wid][3] = s3;
  }
  __syncthreads();
  if (tid == 0) {
    double a0 = wsum[0][0] + wsum[1][0] + wsum[2][0] + wsum[3][0];
    double a1 = wsum[0][1] + wsum[1][1] + wsum[2][1] + wsum[3][1];
    double a2 = wsum[0][2] + wsum[1][2] + wsum[2][2] + wsum[3][2];
    double a3 = wsum[0][3] + wsum[1][3] + wsum[2][3] + wsum[3][3];
    out[0] = (float)(a0 / (double)NROW);
    out[1] = (float)(1.0 - a1 / (double)NROW);
    out[2] = (float)(a2 / ((double)NROW * 3.0));
    out[3] = (float)(a3 / ((double)NROW * (double)KNEG));
  }
}

extern "C" void kernel_launch(void* const* d_in, const int* in_sizes, int n_in,
                              void* d_out, int out_size, void* d_ws, size_t ws_size,
                              hipStream_t stream) {
  (void)in_sizes; (void)n_in; (void)out_size;
  const float* X = (const float*)d_in[0];
  float* out = (float*)d_out;
  char* ws = (char*)d_ws;

  ushort* distb = (ushort*)ws;                                     // 32 MiB bf16
  size_t off = (size_t)NROW * NROW * sizeof(ushort);
  float* sq = (float*)(ws + off);            off += NROW * sizeof(float);
  ushort* Xbf = (ushort*)(ws + off);         off += (size_t)NROW * NDIM * sizeof(ushort);
  float4* part = (float4*)(ws + off);        off += (size_t)NROW * sizeof(float4);
  // fp16 Gumbel table (32 MB) — only if workspace allows; else inline fallback
  ushort* Gh = nullptr;
  if (ws_size >= off + GTOT * sizeof(ushort)) Gh = (ushort*)(ws + off);

  prep_kernel<<<NROW, 64, 0, stream>>>(X, sq, Xbf);
  dist_gumbel<<<DISTBLKS, 256, 0, stream>>>(Xbf, sq, distb, Gh);
  row_kernel<<<NROW, 256, 0, stream>>>(distb, Gh, part);
  reduce_kernel<<<1, 256, 0, stream>>>(part, out);
}